// Round 5
// baseline (315.789 us; speedup 1.0000x reference)
//
#include <hip/hip_runtime.h>
#include <hip/hip_bf16.h>
#include <cstdint>

// Problem constants
#define Ln 2048
#define Bn 64
#define Kd 256
#define Vd 256
#define Hn 8

#define CH 64    // l-rows per fused chunk
#define NCH 32   // number of chunks (Ln / CH)

using u32 = unsigned int;
using u16 = unsigned short;

__device__ __forceinline__ float bflo(u32 u) { return __uint_as_float(u << 16); }
__device__ __forceinline__ float bfhi(u32 u) { return __uint_as_float(u & 0xffff0000u); }
__device__ __forceinline__ float bf1(u16 s) { return __uint_as_float(((u32)s) << 16); }
__device__ __forceinline__ float dot4(float4 a, float4 b) {
  return a.x * b.x + a.y * b.y + a.z * b.z + a.w * b.w;
}

// Device-side dtype sniff on `keys` (little-endian aware): u16[2i] is the LOW
// mantissa half of float[i] for fp32 data -> ~14% sane-bf16; for genuine bf16
// data it's a real N(0,1) value -> ~100% sane. (Rounds 1-3 verified: fp32.)
__device__ __forceinline__ bool sniff_bf16(const void* keys) {
  const u16* q = (const u16*)keys;
  int lane = threadIdx.x & 63;
  u16 u = q[2 * (lane * 127)];
  u32 e = (u >> 7) & 0xff;
  bool sane = (u == 0) || (e >= 100 && e <= 134);
  return __popcll(__ballot(sane)) > 32;
}

// ---------------------------------------------------------------------------
// k_prep: q = query @ Wq + bq  (fp32 in ws)   grid (4 chunks, 64 b), block 256
__global__ __launch_bounds__(256) void k_prep(const void* keys, const void* query,
                                              const void* Wq, const void* bq,
                                              float* q_ws) {
  const bool bf = sniff_bf16(keys);
  const int t = threadIdx.x;
  const int chunk = blockIdx.x;  // 0..3
  const int b = blockIdx.y;      // 0..63

  __shared__ float ql[256];
  ql[t] = bf ? bf1(((const u16*)query)[b * 256 + t]) : ((const float*)query)[b * 256 + t];
  __syncthreads();

  int c0 = chunk * 512 + 2 * t;  // two output columns per thread
  float a0, a1;
  if (bf) { a0 = bf1(((const u16*)bq)[c0]); a1 = bf1(((const u16*)bq)[c0 + 1]); }
  else    { a0 = ((const float*)bq)[c0];    a1 = ((const float*)bq)[c0 + 1]; }

  if (bf) {
    const u32* w = (const u32*)Wq + chunk * 256 + t;
    for (int k0 = 0; k0 < 256; k0 += 16) {
      u32 wv[16];
#pragma unroll
      for (int j = 0; j < 16; j++) wv[j] = w[(size_t)(k0 + j) * 1024];
#pragma unroll
      for (int j = 0; j < 16; j++) {
        float qk = ql[k0 + j];
        a0 += qk * bflo(wv[j]); a1 += qk * bfhi(wv[j]);
      }
    }
  } else {
    const float2* w = (const float2*)Wq + chunk * 256 + t;
    for (int k0 = 0; k0 < 256; k0 += 16) {
      float2 wv[16];
#pragma unroll
      for (int j = 0; j < 16; j++) wv[j] = w[(size_t)(k0 + j) * 1024];
#pragma unroll
      for (int j = 0; j < 16; j++) {
        float qk = ql[k0 + j];
        a0 += qk * wv[j].x; a1 += qk * wv[j].y;
      }
    }
  }
  q_ws[b * 2048 + c0] = a0;
  q_ws[b * 2048 + c0 + 1] = a1;
}

// ---------------------------------------------------------------------------
// k_fused v5: INVERTED staging. q lives in LDS (8 KB, one fill barrier);
// keys live in per-lane registers (lane=(r8,ks8), row=wave*8+r8, interleaved
// k-slice j*32+ks8*4 -> 128B-contiguous loads per 8-lane group, 8 independent
// float4 in flight). ZERO barriers in the score phase (no shared keys tile).
// q_lds reads: fixed (h,j) per instr -> r8-broadcast x 8-distinct-bank,
// conflict-free. Score reduce = 3 shfl_xor over ks8. Batch-0 loads hoisted
// above the fill barrier; batch-1 loads issue before batch-0 compute.
// LDS 37.4 -> ~11.5 KB (residency now VGPR-limited, ~5 blk/CU), barriers 7->3.
// Spill guards (rounds 1-4): no lambdas, no address-taken reg arrays, no
// launch_bounds min-waves arg, named registers only in hot paths.
__global__ __launch_bounds__(256) void k_fused(const void* keys, const void* vals,
                                               const void* rpe, const int* steps,
                                               const float* q_ws, float* O_part,
                                               float2* mz_part) {
  const int b = blockIdx.y, chunk = blockIdx.x;
  const int lstart = chunk * CH;
  const int stepb = steps[b];
  if (lstart >= stepb) return;  // dead chunk
  const int lcnt = min(CH, stepb - lstart);
  const bool bf = sniff_bf16(keys);
  const int t = threadIdx.x;
  const int lane = t & 63;
  const int wave = __builtin_amdgcn_readfirstlane(t >> 6);  // 0..3

  __shared__ __align__(16) float q_lds[Hn * Kd];  // 8 KB
  __shared__ __align__(16) float w_lds[CH * 12];  // scores -> weights (3 KB)
  __shared__ float rpe_lds[CH];
  __shared__ float2 mz_lds[8];

  const int r8 = lane >> 3, ks8 = lane & 7;

// ---- load one 32-row batch of keys into 8 named float4 regs (prefix P) ----
#define LOAD_K(P, BB)                                                         \
  float4 P##0, P##1, P##2, P##3, P##4, P##5, P##6, P##7;                      \
  do {                                                                        \
    const int row_ = (BB) * 32 + wave * 8 + r8;                               \
    if (bf) {                                                                 \
      const u16* kb = (const u16*)keys +                                      \
          ((size_t)(lstart + row_) * 64 + b) * 256 + ks8 * 4;                 \
      uint2 u0 = *(const uint2*)(kb + 0);   uint2 u1 = *(const uint2*)(kb + 32);  \
      uint2 u2 = *(const uint2*)(kb + 64);  uint2 u3 = *(const uint2*)(kb + 96);  \
      uint2 u4 = *(const uint2*)(kb + 128); uint2 u5 = *(const uint2*)(kb + 160); \
      uint2 u6 = *(const uint2*)(kb + 192); uint2 u7 = *(const uint2*)(kb + 224); \
      P##0 = make_float4(bflo(u0.x), bfhi(u0.x), bflo(u0.y), bfhi(u0.y));     \
      P##1 = make_float4(bflo(u1.x), bfhi(u1.x), bflo(u1.y), bfhi(u1.y));     \
      P##2 = make_float4(bflo(u2.x), bfhi(u2.x), bflo(u2.y), bfhi(u2.y));     \
      P##3 = make_float4(bflo(u3.x), bfhi(u3.x), bflo(u3.y), bfhi(u3.y));     \
      P##4 = make_float4(bflo(u4.x), bfhi(u4.x), bflo(u4.y), bfhi(u4.y));     \
      P##5 = make_float4(bflo(u5.x), bfhi(u5.x), bflo(u5.y), bfhi(u5.y));     \
      P##6 = make_float4(bflo(u6.x), bfhi(u6.x), bflo(u6.y), bfhi(u6.y));     \
      P##7 = make_float4(bflo(u7.x), bfhi(u7.x), bflo(u7.y), bfhi(u7.y));     \
    } else {                                                                  \
      const float* kb = (const float*)keys +                                  \
          ((size_t)(lstart + row_) * 64 + b) * 256 + ks8 * 4;                 \
      P##0 = *(const float4*)(kb + 0);   P##1 = *(const float4*)(kb + 32);    \
      P##2 = *(const float4*)(kb + 64);  P##3 = *(const float4*)(kb + 96);    \
      P##4 = *(const float4*)(kb + 128); P##5 = *(const float4*)(kb + 160);   \
      P##6 = *(const float4*)(kb + 192); P##7 = *(const float4*)(kb + 224);   \
    }                                                                         \
  } while (0)

#define QF(H, J) (*(const float4*)(qp + (H) * 256 + (J) * 32))
#define SCH(P, H)                                                             \
  (dot4(P##0, QF(H, 0)) + dot4(P##1, QF(H, 1)) + dot4(P##2, QF(H, 2)) +       \
   dot4(P##3, QF(H, 3)) + dot4(P##4, QF(H, 4)) + dot4(P##5, QF(H, 5)) +       \
   dot4(P##6, QF(H, 6)) + dot4(P##7, QF(H, 7)))
#define R3(A)                                                                 \
  A += __shfl_xor(A, 1); A += __shfl_xor(A, 2); A += __shfl_xor(A, 4);

#define COMPUTE_WRITE(P, BB) do {                                             \
    const int row_ = (BB) * 32 + wave * 8 + r8;                               \
    float a0 = SCH(P, 0), a1 = SCH(P, 1), a2 = SCH(P, 2), a3 = SCH(P, 3);     \
    float a4 = SCH(P, 4), a5 = SCH(P, 5), a6 = SCH(P, 6), a7 = SCH(P, 7);     \
    R3(a0) R3(a1) R3(a2) R3(a3) R3(a4) R3(a5) R3(a6) R3(a7)                   \
    if (ks8 == 0) {                                                           \
      float rp = rpe_lds[row_];                                               \
      w_lds[row_ * 12 + 0] = a0 * rp; w_lds[row_ * 12 + 1] = a1 * rp;         \
      w_lds[row_ * 12 + 2] = a2 * rp; w_lds[row_ * 12 + 3] = a3 * rp;         \
      w_lds[row_ * 12 + 4] = a4 * rp; w_lds[row_ * 12 + 5] = a5 * rp;         \
      w_lds[row_ * 12 + 6] = a6 * rp; w_lds[row_ * 12 + 7] = a7 * rp;         \
    }                                                                         \
  } while (0)

  // batch-0 keys loads issue BEFORE the fill barrier (independent of LDS)
  LOAD_K(p, 0);

  // q_lds fill: 256 threads x 8 contiguous floats (coalesced), plus rpe
  {
    const float4* src = (const float4*)(q_ws + (size_t)b * 2048) + t * 2;
    float4 f0 = src[0], f1 = src[1];
    *((float4*)q_lds + t * 2) = f0;
    *((float4*)q_lds + t * 2 + 1) = f1;
  }
  if (t < CH) {
    int l = lstart + t;
    rpe_lds[t] = bf ? bf1(((const u16*)rpe)[l * 64 + b]) : ((const float*)rpe)[l * 64 + b];
  }
  __syncthreads();

  const float* qp = q_lds + ks8 * 4;

  LOAD_K(s, 1);           // batch-1 loads in flight during batch-0 compute
  COMPUTE_WRITE(p, 0);
  COMPUTE_WRITE(s, 1);
  __syncthreads();

  // ================= partial softmax: 32 threads per h over 64 rows ==========
  {
    const int h = t >> 5, j = t & 31;
    float s0 = (j < lcnt) ? w_lds[j * 12 + h] : -3.0e38f;
    float s1 = (j + 32 < lcnt) ? w_lds[(j + 32) * 12 + h] : -3.0e38f;
    float m = fmaxf(s0, s1);
#pragma unroll
    for (int off = 16; off >= 1; off >>= 1) m = fmaxf(m, __shfl_xor(m, off, 32));
    float e0 = (j < lcnt) ? __expf(s0 - m) : 0.f;
    float e1 = (j + 32 < lcnt) ? __expf(s1 - m) : 0.f;
    w_lds[j * 12 + h] = e0;          // dead rows get 0
    w_lds[(j + 32) * 12 + h] = e1;
    float zs = e0 + e1;
#pragma unroll
    for (int off = 16; off >= 1; off >>= 1) zs += __shfl_xor(zs, off, 32);
    if (j == 0) mz_lds[h] = make_float2(m, zs);
  }
  __syncthreads();
  if (t < 8) mz_part[((size_t)chunk * 64 + b) * 8 + t] = mz_lds[t];

  // ================= read phase: O_c[h][v] = sum_l w[l][h]*vals[l][v] ========
  // wave owns v-slice [wave*64, wave*64+64); lane = (rg = lane>>4, vslot = lane&15)
  const int vslot = lane & 15, rg = lane >> 4;
  float acc[8][4];
#pragma unroll
  for (int hh = 0; hh < 8; hh++)
#pragma unroll
    for (int cc = 0; cc < 4; cc++) acc[hh][cc] = 0.f;

  if (bf) {
    const u32* vb = (const u32*)vals + ((size_t)lstart * 64 + b) * 128 + wave * 32 + vslot * 2;
    for (int i0 = 0; i0 < 16; i0 += 8) {
      uint2 uu[8];
#pragma unroll
      for (int jb = 0; jb < 8; jb++) {
        int row = rg + 4 * (i0 + jb);
        uu[jb] = *(const uint2*)(vb + (size_t)row * 8192);
      }
#pragma unroll
      for (int jb = 0; jb < 8; jb++) {
        int row = rg + 4 * (i0 + jb);
        float4 w0 = *(const float4*)&w_lds[row * 12];
        float4 w1 = *(const float4*)&w_lds[row * 12 + 4];
        float v0 = bflo(uu[jb].x), v1 = bfhi(uu[jb].x);
        float v2 = bflo(uu[jb].y), v3 = bfhi(uu[jb].y);
        acc[0][0] += w0.x * v0; acc[0][1] += w0.x * v1; acc[0][2] += w0.x * v2; acc[0][3] += w0.x * v3;
        acc[1][0] += w0.y * v0; acc[1][1] += w0.y * v1; acc[1][2] += w0.y * v2; acc[1][3] += w0.y * v3;
        acc[2][0] += w0.z * v0; acc[2][1] += w0.z * v1; acc[2][2] += w0.z * v2; acc[2][3] += w0.z * v3;
        acc[3][0] += w0.w * v0; acc[3][1] += w0.w * v1; acc[3][2] += w0.w * v2; acc[3][3] += w0.w * v3;
        acc[4][0] += w1.x * v0; acc[4][1] += w1.x * v1; acc[4][2] += w1.x * v2; acc[4][3] += w1.x * v3;
        acc[5][0] += w1.y * v0; acc[5][1] += w1.y * v1; acc[5][2] += w1.y * v2; acc[5][3] += w1.y * v3;
        acc[6][0] += w1.z * v0; acc[6][1] += w1.z * v1; acc[6][2] += w1.z * v2; acc[6][3] += w1.z * v3;
        acc[7][0] += w1.w * v0; acc[7][1] += w1.w * v1; acc[7][2] += w1.w * v2; acc[7][3] += w1.w * v3;
      }
    }
  } else {
    const float* vb = (const float*)vals + ((size_t)lstart * 64 + b) * 256 + wave * 64 + vslot * 4;
    for (int i0 = 0; i0 < 16; i0 += 8) {
      float4 vv[8];
#pragma unroll
      for (int jb = 0; jb < 8; jb++) {
        int row = rg + 4 * (i0 + jb);
        vv[jb] = *(const float4*)(vb + (size_t)row * 16384);
      }
#pragma unroll
      for (int jb = 0; jb < 8; jb++) {
        int row = rg + 4 * (i0 + jb);
        float4 w0 = *(const float4*)&w_lds[row * 12];
        float4 w1 = *(const float4*)&w_lds[row * 12 + 4];
        acc[0][0] += w0.x * vv[jb].x; acc[0][1] += w0.x * vv[jb].y; acc[0][2] += w0.x * vv[jb].z; acc[0][3] += w0.x * vv[jb].w;
        acc[1][0] += w0.y * vv[jb].x; acc[1][1] += w0.y * vv[jb].y; acc[1][2] += w0.y * vv[jb].z; acc[1][3] += w0.y * vv[jb].w;
        acc[2][0] += w0.z * vv[jb].x; acc[2][1] += w0.z * vv[jb].y; acc[2][2] += w0.z * vv[jb].z; acc[2][3] += w0.z * vv[jb].w;
        acc[3][0] += w0.w * vv[jb].x; acc[3][1] += w0.w * vv[jb].y; acc[3][2] += w0.w * vv[jb].z; acc[3][3] += w0.w * vv[jb].w;
        acc[4][0] += w1.x * vv[jb].x; acc[4][1] += w1.x * vv[jb].y; acc[4][2] += w1.x * vv[jb].z; acc[4][3] += w1.x * vv[jb].w;
        acc[5][0] += w1.y * vv[jb].x; acc[5][1] += w1.y * vv[jb].y; acc[5][2] += w1.y * vv[jb].z; acc[5][3] += w1.y * vv[jb].w;
        acc[6][0] += w1.z * vv[jb].x; acc[6][1] += w1.z * vv[jb].y; acc[6][2] += w1.z * vv[jb].z; acc[6][3] += w1.z * vv[jb].w;
        acc[7][0] += w1.w * vv[jb].x; acc[7][1] += w1.w * vv[jb].y; acc[7][2] += w1.w * vv[jb].z; acc[7][3] += w1.w * vv[jb].w;
      }
    }
  }

  // in-wave combine over 4 row-groups, then 16 lanes store the wave's v-slice
#pragma unroll
  for (int hh = 0; hh < 8; hh++)
#pragma unroll
    for (int cc = 0; cc < 4; cc++) {
      float v = acc[hh][cc];
      v += __shfl_xor(v, 16);
      v += __shfl_xor(v, 32);
      acc[hh][cc] = v;
    }
  if (rg == 0) {
    float* op = O_part + ((size_t)chunk * 64 + b) * 2048 + wave * 64 + vslot * 4;
#pragma unroll
    for (int hh = 0; hh < 8; hh++) {
      float4 o = make_float4(acc[hh][0], acc[hh][1], acc[hh][2], acc[hh][3]);
      *(float4*)&op[hh * 256] = o;
    }
  }
}

// ---------------------------------------------------------------------------
// k_out1: per (h,b): combine 32 chunk partials -> rn[256]; out_part = rn @ Wa
// grid (8 h, 64 b), block 256 (one output column each). Batched loads.
__global__ __launch_bounds__(256) void k_out1(const void* keys, const void* Wa,
                                              const int* steps, const float* O_part,
                                              const float2* mz_part, float* out_part) {
  const int h = blockIdx.x, b = blockIdx.y;
  const bool bf = sniff_bf16(keys);
  const int t = threadIdx.x;  // 0..255 = output column
  const int nlive = (steps[b] + CH - 1) >> 6;  // 1..32

  // chunk scale factors (uniform scalar work, all threads redundant)
  float2 mzv[NCH];
#pragma unroll
  for (int c = 0; c < NCH; c++)
    mzv[c] = (c < nlive) ? mz_part[((size_t)c * 64 + b) * 8 + h] : make_float2(-3.0e38f, 0.f);
  float M = -3.0e38f;
#pragma unroll
  for (int c = 0; c < NCH; c++) M = fmaxf(M, mzv[c].x);
  float sc[NCH];
  float Z = 0.f;
#pragma unroll
  for (int c = 0; c < NCH; c++) {
    sc[c] = __expf(mzv[c].x - M);
    Z += sc[c] * mzv[c].y;
  }
  const float zi = 1.0f / Z;

  // combine O_part chunks (two batches of 16 independent loads)
  __shared__ float rn[256];
  {
    const float* op = O_part + (size_t)b * 2048 + h * 256 + t;
    float s = 0.f;
    float ov[16];
#pragma unroll
    for (int c = 0; c < 16; c++) ov[c] = (c < nlive) ? op[(size_t)c * 131072] : 0.f;
#pragma unroll
    for (int c = 0; c < 16; c++) s += sc[c] * ov[c];
#pragma unroll
    for (int c = 0; c < 16; c++) ov[c] = (c + 16 < nlive) ? op[(size_t)(c + 16) * 131072] : 0.f;
#pragma unroll
    for (int c = 0; c < 16; c++) s += sc[c + 16] * ov[c];
    rn[t] = s * zi;
  }
  __syncthreads();

  float a = 0.f;
  if (bf) {
    const u32* wa = (const u32*)Wa + (size_t)(h * 256) * 128 + (t >> 1);
    const bool hi = (t & 1);
    for (int c0 = 0; c0 < 256; c0 += 16) {
      u32 wv[16];
#pragma unroll
      for (int j = 0; j < 16; j++) wv[j] = wa[(size_t)(c0 + j) * 128];
#pragma unroll
      for (int j = 0; j < 16; j++)
        a += rn[c0 + j] * (hi ? bfhi(wv[j]) : bflo(wv[j]));
    }
  } else {
    const float* wa = (const float*)Wa + (size_t)(h * 256) * 256 + t;
    for (int c0 = 0; c0 < 256; c0 += 16) {
      float wv[16];
#pragma unroll
      for (int j = 0; j < 16; j++) wv[j] = wa[(size_t)(c0 + j) * 256];
#pragma unroll
      for (int j = 0; j < 16; j++) a += rn[c0 + j] * wv[j];
    }
  }
  out_part[(size_t)(h * 64 + b) * 256 + t] = a;
}

// ---------------------------------------------------------------------------
// k_out2: out[b,v] = sum_h out_part[h][b][v] + ba[v]   (dtype by sniff)
// grid 64, block 256
__global__ __launch_bounds__(256) void k_out2(const void* keys, const void* ba,
                                              const float* out_part, void* out) {
  const int b = blockIdx.x, t = threadIdx.x;
  const bool bf = sniff_bf16(keys);
  float s = bf ? bf1(((const u16*)ba)[t]) : ((const float*)ba)[t];
  float ov[8];
#pragma unroll
  for (int h = 0; h < 8; h++) ov[h] = out_part[(size_t)(h * 64 + b) * 256 + t];
#pragma unroll
  for (int h = 0; h < 8; h++) s += ov[h];
  if (bf)
    ((__hip_bfloat16*)out)[b * 256 + t] = __float2bfloat16(s);
  else
    ((float*)out)[b * 256 + t] = s;
}

// ---------------------------------------------------------------------------
extern "C" void kernel_launch(void* const* d_in, const int* in_sizes, int n_in,
                              void* d_out, int out_size, void* d_ws, size_t ws_size,
                              hipStream_t stream) {
  (void)in_sizes; (void)n_in; (void)out_size; (void)ws_size;
  const void* query = d_in[0];
  const void* keys = d_in[1];
  const void* vals = d_in[2];
  const void* rpe = d_in[3];
  const void* Wq = d_in[4];
  const void* bq = d_in[5];
  const void* Wa = d_in[6];
  const void* ba = d_in[7];
  const int* steps = (const int*)d_in[8];

  float* ws = (float*)d_ws;
  float* q_ws = ws;                                  // 131072 f
  float* O_part = ws + 131072;                       // 4194304 f (32 chunks x 64 b x 2048)
  float2* mz_part = (float2*)(ws + 131072 + 4194304);  // 32768 f
  float* out_part = ws + 131072 + 4194304 + 32768;   // 131072 f  (total ~18 MB)

  k_prep<<<dim3(4, 64), 256, 0, stream>>>(keys, query, Wq, bq, q_ws);
  k_fused<<<dim3(NCH, 64), 256, 0, stream>>>(keys, vals, rpe, steps, q_ws, O_part, mz_part);
  k_out1<<<dim3(8, 64), 256, 0, stream>>>(keys, Wa, steps, O_part, mz_part, out_part);
  k_out2<<<64, 256, 0, stream>>>(keys, ba, out_part, d_out);
}

// Round 6
// 302.677 us; speedup vs baseline: 1.0433x; 1.0433x over previous
//
#include <hip/hip_runtime.h>
#include <hip/hip_bf16.h>
#include <cstdint>

// Problem constants
#define Ln 2048
#define Bn 64
#define Kd 256
#define Vd 256
#define Hn 8

#define CH 64    // l-rows per chunk
#define NCH 32   // number of chunks (Ln / CH)

using u32 = unsigned int;
using u16 = unsigned short;

__device__ __forceinline__ float bflo(u32 u) { return __uint_as_float(u << 16); }
__device__ __forceinline__ float bfhi(u32 u) { return __uint_as_float(u & 0xffff0000u); }
__device__ __forceinline__ float bf1(u16 s) { return __uint_as_float(((u32)s) << 16); }
__device__ __forceinline__ float dot4(float4 a, float4 b) {
  return a.x * b.x + a.y * b.y + a.z * b.z + a.w * b.w;
}

// Device-side dtype sniff on `keys` (little-endian aware): u16[2i] is the LOW
// mantissa half of float[i] for fp32 data -> ~14% sane-bf16; for genuine bf16
// data it's a real N(0,1) value -> ~100% sane. (Rounds 1-3 verified: fp32.)
__device__ __forceinline__ bool sniff_bf16(const void* keys) {
  const u16* q = (const u16*)keys;
  int lane = threadIdx.x & 63;
  u16 u = q[2 * (lane * 127)];
  u32 e = (u >> 7) & 0xff;
  bool sane = (u == 0) || (e >= 100 && e <= 134);
  return __popcll(__ballot(sane)) > 32;
}

// ---------------------------------------------------------------------------
// k_prep: q = query @ Wq + bq  (fp32 in ws)   grid (4 chunks, 64 b), block 256
__global__ __launch_bounds__(256) void k_prep(const void* keys, const void* query,
                                              const void* Wq, const void* bq,
                                              float* q_ws) {
  const bool bf = sniff_bf16(keys);
  const int t = threadIdx.x;
  const int chunk = blockIdx.x;  // 0..3
  const int b = blockIdx.y;      // 0..63

  __shared__ float ql[256];
  ql[t] = bf ? bf1(((const u16*)query)[b * 256 + t]) : ((const float*)query)[b * 256 + t];
  __syncthreads();

  int c0 = chunk * 512 + 2 * t;  // two output columns per thread
  float a0, a1;
  if (bf) { a0 = bf1(((const u16*)bq)[c0]); a1 = bf1(((const u16*)bq)[c0 + 1]); }
  else    { a0 = ((const float*)bq)[c0];    a1 = ((const float*)bq)[c0 + 1]; }

  if (bf) {
    const u32* w = (const u32*)Wq + chunk * 256 + t;
    for (int k0 = 0; k0 < 256; k0 += 16) {
      u32 wv[16];
#pragma unroll
      for (int j = 0; j < 16; j++) wv[j] = w[(size_t)(k0 + j) * 1024];
#pragma unroll
      for (int j = 0; j < 16; j++) {
        float qk = ql[k0 + j];
        a0 += qk * bflo(wv[j]); a1 += qk * bfhi(wv[j]);
      }
    }
  } else {
    const float2* w = (const float2*)Wq + chunk * 256 + t;
    for (int k0 = 0; k0 < 256; k0 += 16) {
      float2 wv[16];
#pragma unroll
      for (int j = 0; j < 16; j++) wv[j] = w[(size_t)(k0 + j) * 1024];
#pragma unroll
      for (int j = 0; j < 16; j++) {
        float qk = ql[k0 + j];
        a0 += qk * wv[j].x; a1 += qk * wv[j].y;
      }
    }
  }
  q_ws[b * 2048 + c0] = a0;
  q_ws[b * 2048 + c0 + 1] = a1;
}

// ---------------------------------------------------------------------------
// k_fused v6: PERSISTENT multi-chunk blocks. grid (8, 64) = 512 blocks = one
// per residency slot (2 blk/CU at ~184 VGPR) -> all co-resident, no dispatch
// rounds, bounded tail (<=4 chunks/block, group g=(x+b)&7 mixes work across
// XCDs). q_lds filled ONCE per block. Chunk loop is software-pipelined:
//   issue rpe+B1 -> compute B0 -> compute B1 -> issue valsA + next-B0 ->
//   barrier -> softmax (rpe applied here, from regs) -> barrier ->
//   issue valsB -> consume valsA/valsB -> combine -> store -> barrier.
// Every stream is issued one phase before its use; p/n register roles are
// FIXED (B0 always p, B1 always n) so no swap/unroll-2 needed.
// Spill guards (rounds 1-5): no lambdas, no address-taken reg arrays, no
// launch_bounds min-waves arg; arrays only literal-indexed.
__global__ __launch_bounds__(256) void k_fused(const void* keys, const void* vals,
                                               const void* rpe, const int* steps,
                                               const float* q_ws, float* O_part,
                                               float2* mz_part) {
  const int b = blockIdx.y;
  const int stepb = steps[b];
  const int g = (blockIdx.x + b) & 7;
  if (g * CH >= stepb) return;  // no live chunks for this group
  const bool bf = sniff_bf16(keys);
  const int t = threadIdx.x;
  const int lane = t & 63;
  const int wave = __builtin_amdgcn_readfirstlane(t >> 6);  // 0..3

  const int r8 = lane >> 3, ks8 = lane & 7;     // score-phase lane mapping
  const int vslot = lane & 15, rg = lane >> 4;  // read-phase lane mapping
  const int jj = t & 31, hh8 = t >> 5;          // softmax lane mapping

  __shared__ __align__(16) float q_lds[Hn * Kd];  // 8 KB
  __shared__ __align__(16) float w_lds[CH * 12];  // 3 KB

  float4 p0, p1, p2, p3, p4, p5, p6, p7;  // B0 keys (current / prefetched next)
  float4 n0, n1, n2, n3, n4, n5, n6, n7;  // B1 keys

// ---- load one lane-row of keys (8 float4 k-slices) into named regs --------
#define ASSIGN_K(P, LROW) do {                                                \
    if (bf) {                                                                 \
      const u16* kb_ = (const u16*)keys + ((size_t)(LROW) * 64 + b) * 256 + ks8 * 4; \
      uint2 u0_ = *(const uint2*)(kb_ + 0);   uint2 u1_ = *(const uint2*)(kb_ + 32);  \
      uint2 u2_ = *(const uint2*)(kb_ + 64);  uint2 u3_ = *(const uint2*)(kb_ + 96);  \
      uint2 u4_ = *(const uint2*)(kb_ + 128); uint2 u5_ = *(const uint2*)(kb_ + 160); \
      uint2 u6_ = *(const uint2*)(kb_ + 192); uint2 u7_ = *(const uint2*)(kb_ + 224); \
      P##0 = make_float4(bflo(u0_.x), bfhi(u0_.x), bflo(u0_.y), bfhi(u0_.y)); \
      P##1 = make_float4(bflo(u1_.x), bfhi(u1_.x), bflo(u1_.y), bfhi(u1_.y)); \
      P##2 = make_float4(bflo(u2_.x), bfhi(u2_.x), bflo(u2_.y), bfhi(u2_.y)); \
      P##3 = make_float4(bflo(u3_.x), bfhi(u3_.x), bflo(u3_.y), bfhi(u3_.y)); \
      P##4 = make_float4(bflo(u4_.x), bfhi(u4_.x), bflo(u4_.y), bfhi(u4_.y)); \
      P##5 = make_float4(bflo(u5_.x), bfhi(u5_.x), bflo(u5_.y), bfhi(u5_.y)); \
      P##6 = make_float4(bflo(u6_.x), bfhi(u6_.x), bflo(u6_.y), bfhi(u6_.y)); \
      P##7 = make_float4(bflo(u7_.x), bfhi(u7_.x), bflo(u7_.y), bfhi(u7_.y)); \
    } else {                                                                  \
      const float* kb_ = (const float*)keys + ((size_t)(LROW) * 64 + b) * 256 + ks8 * 4; \
      P##0 = *(const float4*)(kb_ + 0);   P##1 = *(const float4*)(kb_ + 32);  \
      P##2 = *(const float4*)(kb_ + 64);  P##3 = *(const float4*)(kb_ + 96);  \
      P##4 = *(const float4*)(kb_ + 128); P##5 = *(const float4*)(kb_ + 160); \
      P##6 = *(const float4*)(kb_ + 192); P##7 = *(const float4*)(kb_ + 224); \
    }                                                                         \
  } while (0)

#define QF(H, J) (*(const float4*)(qp + (H) * 256 + (J) * 32))
#define SCH(P, H)                                                             \
  (dot4(P##0, QF(H, 0)) + dot4(P##1, QF(H, 1)) + dot4(P##2, QF(H, 2)) +       \
   dot4(P##3, QF(H, 3)) + dot4(P##4, QF(H, 4)) + dot4(P##5, QF(H, 5)) +       \
   dot4(P##6, QF(H, 6)) + dot4(P##7, QF(H, 7)))
#define R3(A)                                                                 \
  A += __shfl_xor(A, 1); A += __shfl_xor(A, 2); A += __shfl_xor(A, 4);

#define COMPUTE_WRITE(P, BOFF) do {                                           \
    const int row_ = (BOFF) + wave * 8 + r8;                                  \
    float a0 = SCH(P, 0), a1 = SCH(P, 1), a2 = SCH(P, 2), a3 = SCH(P, 3);     \
    float a4 = SCH(P, 4), a5 = SCH(P, 5), a6 = SCH(P, 6), a7 = SCH(P, 7);     \
    R3(a0) R3(a1) R3(a2) R3(a3) R3(a4) R3(a5) R3(a6) R3(a7)                   \
    if (ks8 == 0) {                                                           \
      w_lds[row_ * 12 + 0] = a0; w_lds[row_ * 12 + 1] = a1;                   \
      w_lds[row_ * 12 + 2] = a2; w_lds[row_ * 12 + 3] = a3;                   \
      w_lds[row_ * 12 + 4] = a4; w_lds[row_ * 12 + 5] = a5;                   \
      w_lds[row_ * 12 + 6] = a6; w_lds[row_ * 12 + 7] = a7;                   \
    }                                                                         \
  } while (0)

  int c = g;
  int ls = c * CH;

  // prologue: first chunk's B0 loads issue before (and overlap) the q_lds fill
  ASSIGN_K(p, ls + wave * 8 + r8);
  {
    const float4* src = (const float4*)(q_ws + (size_t)b * 2048) + t * 2;
    float4 f0 = src[0], f1 = src[1];
    *((float4*)q_lds + t * 2) = f0;
    *((float4*)q_lds + t * 2 + 1) = f1;
  }
  __syncthreads();

  const float* qp = q_lds + ks8 * 4;

  for (;;) {
    const int lcnt = min(CH, stepb - ls);
    const bool lastc = (c + 8 >= NCH) || ((c + 8) * CH >= stepb);

    // rpe for this chunk's softmax (issued first; used ~2 phases later)
    float rpA, rpB;
    if (bf) {
      rpA = bf1(((const u16*)rpe)[(size_t)(ls + jj) * 64 + b]);
      rpB = bf1(((const u16*)rpe)[(size_t)(ls + jj + 32) * 64 + b]);
    } else {
      rpA = ((const float*)rpe)[(size_t)(ls + jj) * 64 + b];
      rpB = ((const float*)rpe)[(size_t)(ls + jj + 32) * 64 + b];
    }

    ASSIGN_K(n, ls + 32 + wave * 8 + r8);  // B1 issues; hides under B0 compute
    COMPUTE_WRITE(p, 0);                   // B0 (loads issued one phase ago)
    COMPUTE_WRITE(n, 32);                  // B1

    // vals batch A + next chunk's B0 issue BEFORE the barrier/softmax
    float4 va[8];
    const float* vbf = (const float*)vals + ((size_t)ls * 64 + b) * 256 + wave * 64 + vslot * 4;
    if (!bf) {
#pragma unroll
      for (int jb = 0; jb < 8; jb++)
        va[jb] = *(const float4*)(vbf + (size_t)(rg + 4 * jb) * 16384);
    }
    if (!lastc) ASSIGN_K(p, ls + 512 + wave * 8 + r8);
    __syncthreads();

    // ---- partial softmax: 32 threads per h over 64 rows (rpe applied here) --
    {
      float s0 = (jj < lcnt) ? w_lds[jj * 12 + hh8] * rpA : -3.0e38f;
      float s1 = (jj + 32 < lcnt) ? w_lds[(jj + 32) * 12 + hh8] * rpB : -3.0e38f;
      float m = fmaxf(s0, s1);
#pragma unroll
      for (int off = 16; off >= 1; off >>= 1) m = fmaxf(m, __shfl_xor(m, off, 32));
      float e0 = (jj < lcnt) ? __expf(s0 - m) : 0.f;
      float e1 = (jj + 32 < lcnt) ? __expf(s1 - m) : 0.f;
      w_lds[jj * 12 + hh8] = e0;          // dead rows get 0
      w_lds[(jj + 32) * 12 + hh8] = e1;
      float zs = e0 + e1;
#pragma unroll
      for (int off = 16; off >= 1; off >>= 1) zs += __shfl_xor(zs, off, 32);
      if (jj == 0) mz_part[((size_t)c * 64 + b) * 8 + hh8] = make_float2(m, zs);
    }
    __syncthreads();

    // ---- read phase: O_c[h][v] = sum_l w[l][h]*vals[l][v] -------------------
    float acc[8][4];
#pragma unroll
    for (int hh = 0; hh < 8; hh++)
#pragma unroll
      for (int cc = 0; cc < 4; cc++) acc[hh][cc] = 0.f;

    if (bf) {
      const u32* vb = (const u32*)vals + ((size_t)ls * 64 + b) * 128 + wave * 32 + vslot * 2;
      for (int i0 = 0; i0 < 16; i0 += 8) {
        uint2 uu[8];
#pragma unroll
        for (int jb = 0; jb < 8; jb++) {
          int row = rg + 4 * (i0 + jb);
          uu[jb] = *(const uint2*)(vb + (size_t)row * 8192);
        }
#pragma unroll
        for (int jb = 0; jb < 8; jb++) {
          int row = rg + 4 * (i0 + jb);
          float4 w0 = *(const float4*)&w_lds[row * 12];
          float4 w1 = *(const float4*)&w_lds[row * 12 + 4];
          float v0 = bflo(uu[jb].x), v1 = bfhi(uu[jb].x);
          float v2 = bflo(uu[jb].y), v3 = bfhi(uu[jb].y);
          acc[0][0] += w0.x * v0; acc[0][1] += w0.x * v1; acc[0][2] += w0.x * v2; acc[0][3] += w0.x * v3;
          acc[1][0] += w0.y * v0; acc[1][1] += w0.y * v1; acc[1][2] += w0.y * v2; acc[1][3] += w0.y * v3;
          acc[2][0] += w0.z * v0; acc[2][1] += w0.z * v1; acc[2][2] += w0.z * v2; acc[2][3] += w0.z * v3;
          acc[3][0] += w0.w * v0; acc[3][1] += w0.w * v1; acc[3][2] += w0.w * v2; acc[3][3] += w0.w * v3;
          acc[4][0] += w1.x * v0; acc[4][1] += w1.x * v1; acc[4][2] += w1.x * v2; acc[4][3] += w1.x * v3;
          acc[5][0] += w1.y * v0; acc[5][1] += w1.y * v1; acc[5][2] += w1.y * v2; acc[5][3] += w1.y * v3;
          acc[6][0] += w1.z * v0; acc[6][1] += w1.z * v1; acc[6][2] += w1.z * v2; acc[6][3] += w1.z * v3;
          acc[7][0] += w1.w * v0; acc[7][1] += w1.w * v1; acc[7][2] += w1.w * v2; acc[7][3] += w1.w * v3;
        }
      }
    } else {
      // batch B issues first (in flight during batch-A consumption)
      float4 vbb[8];
#pragma unroll
      for (int jb = 0; jb < 8; jb++)
        vbb[jb] = *(const float4*)(vbf + (size_t)(rg + 4 * (8 + jb)) * 16384);
#pragma unroll
      for (int jb = 0; jb < 8; jb++) {
        int row = rg + 4 * jb;
        float4 w0 = *(const float4*)&w_lds[row * 12];
        float4 w1 = *(const float4*)&w_lds[row * 12 + 4];
        float4 vv = va[jb];
        acc[0][0] += w0.x * vv.x; acc[0][1] += w0.x * vv.y; acc[0][2] += w0.x * vv.z; acc[0][3] += w0.x * vv.w;
        acc[1][0] += w0.y * vv.x; acc[1][1] += w0.y * vv.y; acc[1][2] += w0.y * vv.z; acc[1][3] += w0.y * vv.w;
        acc[2][0] += w0.z * vv.x; acc[2][1] += w0.z * vv.y; acc[2][2] += w0.z * vv.z; acc[2][3] += w0.z * vv.w;
        acc[3][0] += w0.w * vv.x; acc[3][1] += w0.w * vv.y; acc[3][2] += w0.w * vv.z; acc[3][3] += w0.w * vv.w;
        acc[4][0] += w1.x * vv.x; acc[4][1] += w1.x * vv.y; acc[4][2] += w1.x * vv.z; acc[4][3] += w1.x * vv.w;
        acc[5][0] += w1.y * vv.x; acc[5][1] += w1.y * vv.y; acc[5][2] += w1.y * vv.z; acc[5][3] += w1.y * vv.w;
        acc[6][0] += w1.z * vv.x; acc[6][1] += w1.z * vv.y; acc[6][2] += w1.z * vv.z; acc[6][3] += w1.z * vv.w;
        acc[7][0] += w1.w * vv.x; acc[7][1] += w1.w * vv.y; acc[7][2] += w1.w * vv.z; acc[7][3] += w1.w * vv.w;
      }
#pragma unroll
      for (int jb = 0; jb < 8; jb++) {
        int row = rg + 4 * (8 + jb);
        float4 w0 = *(const float4*)&w_lds[row * 12];
        float4 w1 = *(const float4*)&w_lds[row * 12 + 4];
        float4 vv = vbb[jb];
        acc[0][0] += w0.x * vv.x; acc[0][1] += w0.x * vv.y; acc[0][2] += w0.x * vv.z; acc[0][3] += w0.x * vv.w;
        acc[1][0] += w0.y * vv.x; acc[1][1] += w0.y * vv.y; acc[1][2] += w0.y * vv.z; acc[1][3] += w0.y * vv.w;
        acc[2][0] += w0.z * vv.x; acc[2][1] += w0.z * vv.y; acc[2][2] += w0.z * vv.z; acc[2][3] += w0.z * vv.w;
        acc[3][0] += w0.w * vv.x; acc[3][1] += w0.w * vv.y; acc[3][2] += w0.w * vv.z; acc[3][3] += w0.w * vv.w;
        acc[4][0] += w1.x * vv.x; acc[4][1] += w1.x * vv.y; acc[4][2] += w1.x * vv.z; acc[4][3] += w1.x * vv.w;
        acc[5][0] += w1.y * vv.x; acc[5][1] += w1.y * vv.y; acc[5][2] += w1.y * vv.z; acc[5][3] += w1.y * vv.w;
        acc[6][0] += w1.z * vv.x; acc[6][1] += w1.z * vv.y; acc[6][2] += w1.z * vv.z; acc[6][3] += w1.z * vv.w;
        acc[7][0] += w1.w * vv.x; acc[7][1] += w1.w * vv.y; acc[7][2] += w1.w * vv.z; acc[7][3] += w1.w * vv.w;
      }
    }

    // in-wave combine over 4 row-groups, then 16 lanes store the wave's v-slice
#pragma unroll
    for (int hh = 0; hh < 8; hh++)
#pragma unroll
      for (int cc = 0; cc < 4; cc++) {
        float v = acc[hh][cc];
        v += __shfl_xor(v, 16);
        v += __shfl_xor(v, 32);
        acc[hh][cc] = v;
      }
    if (rg == 0) {
      float* op = O_part + ((size_t)c * 64 + b) * 2048 + wave * 64 + vslot * 4;
#pragma unroll
      for (int hh = 0; hh < 8; hh++) {
        float4 o = make_float4(acc[hh][0], acc[hh][1], acc[hh][2], acc[hh][3]);
        *(float4*)&op[hh * 256] = o;
      }
    }

    if (lastc) break;
    __syncthreads();  // protect w_lds for next chunk's score writes
    c += 8;
    ls += 512;
  }
}

// ---------------------------------------------------------------------------
// k_out1: per (h,b): combine 32 chunk partials -> rn[256]; out_part = rn @ Wa
// grid (8 h, 64 b), block 256 (one output column each). Batched loads.
__global__ __launch_bounds__(256) void k_out1(const void* keys, const void* Wa,
                                              const int* steps, const float* O_part,
                                              const float2* mz_part, float* out_part) {
  const int h = blockIdx.x, b = blockIdx.y;
  const bool bf = sniff_bf16(keys);
  const int t = threadIdx.x;  // 0..255 = output column
  const int nlive = (steps[b] + CH - 1) >> 6;  // 1..32

  // chunk scale factors (uniform scalar work, all threads redundant)
  float2 mzv[NCH];
#pragma unroll
  for (int c = 0; c < NCH; c++)
    mzv[c] = (c < nlive) ? mz_part[((size_t)c * 64 + b) * 8 + h] : make_float2(-3.0e38f, 0.f);
  float M = -3.0e38f;
#pragma unroll
  for (int c = 0; c < NCH; c++) M = fmaxf(M, mzv[c].x);
  float sc[NCH];
  float Z = 0.f;
#pragma unroll
  for (int c = 0; c < NCH; c++) {
    sc[c] = __expf(mzv[c].x - M);
    Z += sc[c] * mzv[c].y;
  }
  const float zi = 1.0f / Z;

  // combine O_part chunks (two batches of 16 independent loads)
  __shared__ float rn[256];
  {
    const float* op = O_part + (size_t)b * 2048 + h * 256 + t;
    float s = 0.f;
    float ov[16];
#pragma unroll
    for (int c = 0; c < 16; c++) ov[c] = (c < nlive) ? op[(size_t)c * 131072] : 0.f;
#pragma unroll
    for (int c = 0; c < 16; c++) s += sc[c] * ov[c];
#pragma unroll
    for (int c = 0; c < 16; c++) ov[c] = (c + 16 < nlive) ? op[(size_t)(c + 16) * 131072] : 0.f;
#pragma unroll
    for (int c = 0; c < 16; c++) s += sc[c + 16] * ov[c];
    rn[t] = s * zi;
  }
  __syncthreads();

  float a = 0.f;
  if (bf) {
    const u32* wa = (const u32*)Wa + (size_t)(h * 256) * 128 + (t >> 1);
    const bool hi = (t & 1);
    for (int c0 = 0; c0 < 256; c0 += 16) {
      u32 wv[16];
#pragma unroll
      for (int j = 0; j < 16; j++) wv[j] = wa[(size_t)(c0 + j) * 128];
#pragma unroll
      for (int j = 0; j < 16; j++)
        a += rn[c0 + j] * (hi ? bfhi(wv[j]) : bflo(wv[j]));
    }
  } else {
    const float* wa = (const float*)Wa + (size_t)(h * 256) * 256 + t;
    for (int c0 = 0; c0 < 256; c0 += 16) {
      float wv[16];
#pragma unroll
      for (int j = 0; j < 16; j++) wv[j] = wa[(size_t)(c0 + j) * 256];
#pragma unroll
      for (int j = 0; j < 16; j++) a += rn[c0 + j] * wv[j];
    }
  }
  out_part[(size_t)(h * 64 + b) * 256 + t] = a;
}

// ---------------------------------------------------------------------------
// k_out2: out[b,v] = sum_h out_part[h][b][v] + ba[v]   (dtype by sniff)
// grid 64, block 256
__global__ __launch_bounds__(256) void k_out2(const void* keys, const void* ba,
                                              const float* out_part, void* out) {
  const int b = blockIdx.x, t = threadIdx.x;
  const bool bf = sniff_bf16(keys);
  float s = bf ? bf1(((const u16*)ba)[t]) : ((const float*)ba)[t];
  float ov[8];
#pragma unroll
  for (int h = 0; h < 8; h++) ov[h] = out_part[(size_t)(h * 64 + b) * 256 + t];
#pragma unroll
  for (int h = 0; h < 8; h++) s += ov[h];
  if (bf)
    ((__hip_bfloat16*)out)[b * 256 + t] = __float2bfloat16(s);
  else
    ((float*)out)[b * 256 + t] = s;
}

// ---------------------------------------------------------------------------
extern "C" void kernel_launch(void* const* d_in, const int* in_sizes, int n_in,
                              void* d_out, int out_size, void* d_ws, size_t ws_size,
                              hipStream_t stream) {
  (void)in_sizes; (void)n_in; (void)out_size; (void)ws_size;
  const void* query = d_in[0];
  const void* keys = d_in[1];
  const void* vals = d_in[2];
  const void* rpe = d_in[3];
  const void* Wq = d_in[4];
  const void* bq = d_in[5];
  const void* Wa = d_in[6];
  const void* ba = d_in[7];
  const int* steps = (const int*)d_in[8];

  float* ws = (float*)d_ws;
  float* q_ws = ws;                                  // 131072 f
  float* O_part = ws + 131072;                       // 4194304 f (32 chunks x 64 b x 2048)
  float2* mz_part = (float2*)(ws + 131072 + 4194304);  // 32768 f
  float* out_part = ws + 131072 + 4194304 + 32768;   // 131072 f  (total ~18 MB)

  k_prep<<<dim3(4, 64), 256, 0, stream>>>(keys, query, Wq, bq, q_ws);
  k_fused<<<dim3(8, 64), 256, 0, stream>>>(keys, vals, rpe, steps, q_ws, O_part, mz_part);
  k_out1<<<dim3(8, 64), 256, 0, stream>>>(keys, Wa, steps, O_part, mz_part, out_part);
  k_out2<<<64, 256, 0, stream>>>(keys, ba, out_part, d_out);
}